// Round 4
// baseline (1179.190 us; speedup 1.0000x reference)
//
#include <hip/hip_runtime.h>

#define N_PTS  (4*1024*1024)
#define NCLUST 65536

// ---------------------------------------------------------------------------
// Kernel 0: zero-fill pooled (ws is re-poisoned 0xAA before every launch).
// ---------------------------------------------------------------------------
__global__ __launch_bounds__(256) void k_zero(float4* __restrict__ p)
{
    p[(size_t)blockIdx.x * 256 + threadIdx.x] = make_float4(0.f, 0.f, 0.f, 0.f);
}

// ---------------------------------------------------------------------------
// Kernel 1: per-point fc0 (3->64) + ReLU fused with sorted segment-max pool.
// Wave = 64 lanes = 64 features; each wave owns 256 contiguous points.
// ALL point/id loads are wave-uniform -> scalar (s_load) via readfirstlane'd
// wave id: 16-point chunks = 12 x 16B-aligned float4 uniform loads. The FMA
// takes the coordinate as its single SGPR operand — no LDS, no broadcasts.
// pooled pre-zeroed: ReLU>=0 makes 0 the max-identity AND the empty-cluster
// fill (reference's isfinite->0 fixup). atomicMax on uint bits == float max
// for non-negative values.
// ---------------------------------------------------------------------------
__global__ __launch_bounds__(256) void k_fc0_pool(
        const float* __restrict__ pts,          // [N,3]
        const int* __restrict__ clus,           // [N] sorted int32, < NCLUST
        const float* __restrict__ W0,           // [3,64]
        const float* __restrict__ b0,           // [64]
        float* __restrict__ pooled)             // [NCLUST,64], pre-zeroed
{
    const int tid  = threadIdx.x;
    const int lane = tid & 63;
    const int w    = __builtin_amdgcn_readfirstlane(tid >> 6);   // wave 0..3
    const int base = blockIdx.x * 1024 + w * 256;                // uniform

    const float w0x = W0[lane];
    const float w0y = W0[64 + lane];
    const float w0z = W0[128 + lane];
    const float bb  = b0[lane];

    unsigned* pool_u = (unsigned*)pooled;

    int   cur  = clus[base];          // uniform -> scalar load
    float vmax = 0.0f;

    #pragma unroll 1
    for (int i = 0; i < 256; i += 16) {
        const int idx = base + i;                 // uniform, idx % 16 == 0
        const int cf = clus[idx];
        const int cl = clus[idx + 15];
        // 16 points = 48 floats = 12 float4, 64B-aligned (idx*12 % 64 == 0)
        const float4* p4 = (const float4*)(pts + (size_t)idx * 3);
        float4 q[12];
        #pragma unroll
        for (int j = 0; j < 12; ++j) q[j] = p4[j];
        const float* qs = (const float*)q;

        if (cf == cl) {                           // chunk is a single run
            if (cf != cur) {                      // run change at chunk edge
                atomicMax(&pool_u[(size_t)cur * 64 + lane], __float_as_uint(vmax));
                vmax = 0.0f;
                cur  = cf;
            }
            float m[16];
            #pragma unroll
            for (int t = 0; t < 16; ++t)
                m[t] = fmaf(qs[3*t], w0x, fmaf(qs[3*t+1], w0y, fmaf(qs[3*t+2], w0z, bb)));
            #pragma unroll
            for (int t = 0; t < 8; ++t) m[t] = fmaxf(m[t], m[t + 8]);
            #pragma unroll
            for (int t = 0; t < 4; ++t) m[t] = fmaxf(m[t], m[t + 4]);
            m[0] = fmaxf(fmaxf(m[0], m[1]), fmaxf(m[2], m[3]));
            vmax = fmaxf(vmax, m[0]);
        } else {                                  // interior boundary: walk
            #pragma unroll 1
            for (int t = 0; t < 16; ++t) {
                const int c = clus[idx + t];      // uniform scalar load
                if (c != cur) {
                    atomicMax(&pool_u[(size_t)cur * 64 + lane], __float_as_uint(vmax));
                    vmax = 0.0f;
                    cur  = c;
                }
                const float h = fmaf(qs[3*t], w0x, fmaf(qs[3*t+1], w0y, fmaf(qs[3*t+2], w0z, bb)));
                vmax = fmaxf(vmax, h);
            }
        }
    }
    atomicMax(&pool_u[(size_t)cur * 64 + lane], __float_as_uint(vmax));
}

// ---------------------------------------------------------------------------
// Kernel 2: fused fc1+fc2, lane = row, weights via scalar (uniform) loads.
// Block = 64 cluster rows x 512 threads (8 waves).
//  Phase A: wave w computes h1 cols [w*16,+16) for all 64 rows; h from LDS
//           Ps (stride 65 -> 2-way banks = free), W1 row-slice uniform ->
//           s_load_dwordx4, FMA with SGPR operand. -> Hs (stride 129).
//  Phase B: wave w computes out cols [w*32,+32); same pattern with W2.
//           W2 is read exactly once per block (no redundancy).
//  Epilogue: acc -> Hs (reused as transpose buffer) -> coalesced float4
//           stores, 2 sweeps of 128 cols.
// LDS = 16.6K (Ps) + 33K (Hs) = 49.7KB -> 3 blocks/CU = 24 waves/CU.
// ---------------------------------------------------------------------------
__global__ __launch_bounds__(512, 6) void k_mlp(
        const float* __restrict__ pooled,
        const float* __restrict__ W1,
        const float* __restrict__ b1,
        const float* __restrict__ W2,
        const float* __restrict__ b2,
        float* __restrict__ out)
{
    __shared__ float Ps[64 * 65];
    __shared__ float Hs[64 * 129];

    const int tid  = threadIdx.x;
    const int lane = tid & 63;                                   // row
    const int w    = __builtin_amdgcn_readfirstlane(tid >> 6);   // wave 0..7
    const int r0b  = blockIdx.x * 64;

    // stage pooled[64 rows][64] -> Ps[64][65] (b32 writes: 2-way banks)
    {
        const float4* src = (const float4*)(pooled + (size_t)r0b * 64);
        #pragma unroll
        for (int j = 0; j < 2; ++j) {
            const int m  = tid + 512 * j;         // float4 index 0..1023
            const float4 v = src[m];
            const int r = m >> 4, c4 = m & 15;
            float* d = &Ps[r * 65 + c4 * 4];
            d[0] = v.x; d[1] = v.y; d[2] = v.z; d[3] = v.w;
        }
    }
    __syncthreads();

    // ---------------- Phase A: fc1 -> Hs ----------------
    {
        const int cb = w * 16;                    // uniform col base
        float accA[16];
        #pragma unroll
        for (int j = 0; j < 4; ++j) {
            const float4 b = *(const float4*)(b1 + cb + 4 * j);
            accA[4*j+0] = b.x; accA[4*j+1] = b.y; accA[4*j+2] = b.z; accA[4*j+3] = b.w;
        }
        #pragma unroll 2
        for (int k = 0; k < 64; ++k) {
            const float h = Ps[lane * 65 + k];    // per-lane row, 2-way free
            const float4 wa = *(const float4*)(W1 + k * 128 + cb);
            const float4 wb = *(const float4*)(W1 + k * 128 + cb + 4);
            const float4 wc = *(const float4*)(W1 + k * 128 + cb + 8);
            const float4 wd = *(const float4*)(W1 + k * 128 + cb + 12);
            accA[ 0] = fmaf(h, wa.x, accA[ 0]);
            accA[ 1] = fmaf(h, wa.y, accA[ 1]);
            accA[ 2] = fmaf(h, wa.z, accA[ 2]);
            accA[ 3] = fmaf(h, wa.w, accA[ 3]);
            accA[ 4] = fmaf(h, wb.x, accA[ 4]);
            accA[ 5] = fmaf(h, wb.y, accA[ 5]);
            accA[ 6] = fmaf(h, wb.z, accA[ 6]);
            accA[ 7] = fmaf(h, wb.w, accA[ 7]);
            accA[ 8] = fmaf(h, wc.x, accA[ 8]);
            accA[ 9] = fmaf(h, wc.y, accA[ 9]);
            accA[10] = fmaf(h, wc.z, accA[10]);
            accA[11] = fmaf(h, wc.w, accA[11]);
            accA[12] = fmaf(h, wd.x, accA[12]);
            accA[13] = fmaf(h, wd.y, accA[13]);
            accA[14] = fmaf(h, wd.z, accA[14]);
            accA[15] = fmaf(h, wd.w, accA[15]);
        }
        #pragma unroll
        for (int j = 0; j < 16; ++j)
            Hs[lane * 129 + cb + j] = fmaxf(accA[j], 0.0f);   // 2-way free
    }
    __syncthreads();

    // ---------------- Phase B: fc2 ----------------
    float acc[32];
    const int cb2 = w * 32;                       // uniform col base
    #pragma unroll
    for (int j = 0; j < 8; ++j) {
        const float4 b = *(const float4*)(b2 + cb2 + 4 * j);
        acc[4*j+0] = b.x; acc[4*j+1] = b.y; acc[4*j+2] = b.z; acc[4*j+3] = b.w;
    }
    #pragma unroll 2
    for (int k = 0; k < 128; ++k) {
        const float h = Hs[lane * 129 + k];       // 2-way free
        #pragma unroll
        for (int j = 0; j < 8; ++j) {
            const float4 wv = *(const float4*)(W2 + (size_t)k * 256 + cb2 + 4 * j);
            acc[4*j+0] = fmaf(h, wv.x, acc[4*j+0]);
            acc[4*j+1] = fmaf(h, wv.y, acc[4*j+1]);
            acc[4*j+2] = fmaf(h, wv.z, acc[4*j+2]);
            acc[4*j+3] = fmaf(h, wv.w, acc[4*j+3]);
        }
    }
    #pragma unroll
    for (int j = 0; j < 32; ++j) acc[j] = fmaxf(acc[j], 0.0f);

    // ---- epilogue: transpose via Hs, coalesced float4 stores (2 sweeps) ----
    #pragma unroll 1
    for (int s = 0; s < 2; ++s) {
        __syncthreads();                          // Hs free / sweep done
        if ((w >> 2) == s) {                      // waves owning cols [s*128,+128)
            const int cl = cb2 - s * 128;
            #pragma unroll
            for (int j = 0; j < 32; ++j)
                Hs[lane * 129 + cl + j] = acc[j];
        }
        __syncthreads();
        #pragma unroll
        for (int it = 0; it < 4; ++it) {
            const int m = tid + 512 * it;         // float4 idx 0..2047
            const int r = m >> 5, c4 = m & 31;
            float4 o;
            o.x = Hs[r * 129 + c4 * 4 + 0];
            o.y = Hs[r * 129 + c4 * 4 + 1];
            o.z = Hs[r * 129 + c4 * 4 + 2];
            o.w = Hs[r * 129 + c4 * 4 + 3];
            *(float4*)(out + (size_t)(r0b + r) * 256 + s * 128 + c4 * 4) = o;
        }
    }
}

// ---------------------------------------------------------------------------
extern "C" void kernel_launch(void* const* d_in, const int* in_sizes, int n_in,
                              void* d_out, int out_size, void* d_ws, size_t ws_size,
                              hipStream_t stream) {
    const float* points  = (const float*)d_in[0];
    const int*   cluster = (const int*)d_in[1];   // int32 on device (harness)
    const float* W0      = (const float*)d_in[2];
    const float* b0      = (const float*)d_in[3];
    const float* W1      = (const float*)d_in[4];
    const float* b1      = (const float*)d_in[5];
    const float* W2      = (const float*)d_in[6];
    const float* b2      = (const float*)d_in[7];
    float* out = (float*)d_out;

    float* pooled = (float*)d_ws;   // 16 MB

    k_zero<<<(NCLUST * 64 / 4) / 256, 256, 0, stream>>>((float4*)pooled);
    k_fc0_pool<<<N_PTS / 1024, 256, 0, stream>>>(points, cluster, W0, b0, pooled);
    k_mlp<<<NCLUST / 64, 512, 0, stream>>>(pooled, W1, b1, W2, b2, out);
}

// Round 5
// 321.801 us; speedup vs baseline: 3.6643x; 3.6643x over previous
//
#include <hip/hip_runtime.h>

#define N_PTS  (4*1024*1024)
#define NCLUST 65536

// ---------------------------------------------------------------------------
// Kernel 0: zero-fill pooled (ws is re-poisoned 0xAA before every launch).
// ---------------------------------------------------------------------------
__global__ __launch_bounds__(256) void k_zero(float4* __restrict__ p)
{
    p[(size_t)blockIdx.x * 256 + threadIdx.x] = make_float4(0.f, 0.f, 0.f, 0.f);
}

// ---------------------------------------------------------------------------
// Kernel 1: per-point fc0 (3->64) + ReLU fused with sorted segment-max pool.
// Wave = 64 lanes = 64 features; each wave owns 256 contiguous points.
// Point/id loads are wave-uniform (scalar s_load candidates). CRITICAL: the
// 12 float4 per chunk are NAMED locals with static .xyzw component access —
// R4's q[12]+float* punning demoted the array to scratch (2.5 GB of private
// memory traffic, 10x slowdown). Never index a local array here.
// pooled pre-zeroed: ReLU>=0 makes 0 the max-identity AND the empty-cluster
// fill. atomicMax on uint bits == float max for non-negative values.
// ---------------------------------------------------------------------------
__global__ __launch_bounds__(256) void k_fc0_pool(
        const float* __restrict__ pts,          // [N,3]
        const int* __restrict__ clus,           // [N] sorted int32, < NCLUST
        const float* __restrict__ W0,           // [3,64]
        const float* __restrict__ b0,           // [64]
        float* __restrict__ pooled)             // [NCLUST,64], pre-zeroed
{
    const int tid  = threadIdx.x;
    const int lane = tid & 63;
    const int w    = __builtin_amdgcn_readfirstlane(tid >> 6);   // wave 0..3
    const int base = blockIdx.x * 1024 + w * 256;                // uniform

    const float w0x = W0[lane];
    const float w0y = W0[64 + lane];
    const float w0z = W0[128 + lane];
    const float bb  = b0[lane];

#define H3(a, b, c) fmaf((a), w0x, fmaf((b), w0y, fmaf((c), w0z, bb)))

    unsigned* pool_u = (unsigned*)pooled;

    int   cur  = clus[base];          // uniform -> scalar load
    float vmax = 0.0f;

    #pragma unroll 1
    for (int i = 0; i < 256; i += 16) {
        const int idx = base + i;                 // uniform, idx % 16 == 0
        const int cf = clus[idx];
        const int cl = clus[idx + 15];

        if (cf == cl) {                           // chunk is a single run
            if (cf != cur) {                      // run change at chunk edge
                atomicMax(&pool_u[(size_t)cur * 64 + lane], __float_as_uint(vmax));
                vmax = 0.0f;
                cur  = cf;
            }
            // 16 points = 48 floats = 12 float4 (16B-aligned: idx*12B%16==0).
            // Named locals + static components only — keeps them in registers.
            const float4* p4 = (const float4*)(pts + (size_t)idx * 3);
            const float4 q0 = p4[0],  q1 = p4[1],  q2  = p4[2],  q3  = p4[3];
            const float4 q4 = p4[4],  q5 = p4[5],  q6  = p4[6],  q7  = p4[7];
            const float4 q8 = p4[8],  q9 = p4[9],  q10 = p4[10], q11 = p4[11];

            float m0  = H3(q0.x,  q0.y,  q0.z);
            float m1  = H3(q0.w,  q1.x,  q1.y);
            float m2  = H3(q1.z,  q1.w,  q2.x);
            float m3  = H3(q2.y,  q2.z,  q2.w);
            float m4  = H3(q3.x,  q3.y,  q3.z);
            float m5  = H3(q3.w,  q4.x,  q4.y);
            float m6  = H3(q4.z,  q4.w,  q5.x);
            float m7  = H3(q5.y,  q5.z,  q5.w);
            float m8  = H3(q6.x,  q6.y,  q6.z);
            float m9  = H3(q6.w,  q7.x,  q7.y);
            float m10 = H3(q7.z,  q7.w,  q8.x);
            float m11 = H3(q8.y,  q8.z,  q8.w);
            float m12 = H3(q9.x,  q9.y,  q9.z);
            float m13 = H3(q9.w,  q10.x, q10.y);
            float m14 = H3(q10.z, q10.w, q11.x);
            float m15 = H3(q11.y, q11.z, q11.w);

            m0  = fmaxf(m0,  m8);  m1  = fmaxf(m1,  m9);
            m2  = fmaxf(m2,  m10); m3  = fmaxf(m3,  m11);
            m4  = fmaxf(m4,  m12); m5  = fmaxf(m5,  m13);
            m6  = fmaxf(m6,  m14); m7  = fmaxf(m7,  m15);
            m0  = fmaxf(m0,  m4);  m1  = fmaxf(m1,  m5);
            m2  = fmaxf(m2,  m6);  m3  = fmaxf(m3,  m7);
            vmax = fmaxf(vmax, fmaxf(fmaxf(m0, m1), fmaxf(m2, m3)));
        } else {                                  // interior boundary: walk
            #pragma unroll 1
            for (int t = 0; t < 16; ++t) {
                const int c = clus[idx + t];      // uniform scalar load
                if (c != cur) {
                    atomicMax(&pool_u[(size_t)cur * 64 + lane], __float_as_uint(vmax));
                    vmax = 0.0f;
                    cur  = c;
                }
                const size_t o = (size_t)(idx + t) * 3;
                const float h = H3(pts[o], pts[o + 1], pts[o + 2]);
                vmax = fmaxf(vmax, h);
            }
        }
    }
    atomicMax(&pool_u[(size_t)cur * 64 + lane], __float_as_uint(vmax));
#undef H3
}

// ---------------------------------------------------------------------------
// Kernel 2: fused fc1+fc2, lane = row, weights via scalar (uniform) loads.
// Block = 64 cluster rows x 512 threads (8 waves).  (unchanged from R4 —
// counters for it will surface next round once fc0 shrinks)
// ---------------------------------------------------------------------------
__global__ __launch_bounds__(512, 6) void k_mlp(
        const float* __restrict__ pooled,
        const float* __restrict__ W1,
        const float* __restrict__ b1,
        const float* __restrict__ W2,
        const float* __restrict__ b2,
        float* __restrict__ out)
{
    __shared__ float Ps[64 * 65];
    __shared__ float Hs[64 * 129];

    const int tid  = threadIdx.x;
    const int lane = tid & 63;                                   // row
    const int w    = __builtin_amdgcn_readfirstlane(tid >> 6);   // wave 0..7
    const int r0b  = blockIdx.x * 64;

    // stage pooled[64 rows][64] -> Ps[64][65] (b32 writes: 2-way banks)
    {
        const float4* src = (const float4*)(pooled + (size_t)r0b * 64);
        #pragma unroll
        for (int j = 0; j < 2; ++j) {
            const int m  = tid + 512 * j;         // float4 index 0..1023
            const float4 v = src[m];
            const int r = m >> 4, c4 = m & 15;
            float* d = &Ps[r * 65 + c4 * 4];
            d[0] = v.x; d[1] = v.y; d[2] = v.z; d[3] = v.w;
        }
    }
    __syncthreads();

    // ---------------- Phase A: fc1 -> Hs ----------------
    {
        const int cb = w * 16;                    // uniform col base
        float accA[16];
        #pragma unroll
        for (int j = 0; j < 4; ++j) {
            const float4 b = *(const float4*)(b1 + cb + 4 * j);
            accA[4*j+0] = b.x; accA[4*j+1] = b.y; accA[4*j+2] = b.z; accA[4*j+3] = b.w;
        }
        #pragma unroll 2
        for (int k = 0; k < 64; ++k) {
            const float h = Ps[lane * 65 + k];    // per-lane row, 2-way free
            const float4 wa = *(const float4*)(W1 + k * 128 + cb);
            const float4 wb = *(const float4*)(W1 + k * 128 + cb + 4);
            const float4 wc = *(const float4*)(W1 + k * 128 + cb + 8);
            const float4 wd = *(const float4*)(W1 + k * 128 + cb + 12);
            accA[ 0] = fmaf(h, wa.x, accA[ 0]);
            accA[ 1] = fmaf(h, wa.y, accA[ 1]);
            accA[ 2] = fmaf(h, wa.z, accA[ 2]);
            accA[ 3] = fmaf(h, wa.w, accA[ 3]);
            accA[ 4] = fmaf(h, wb.x, accA[ 4]);
            accA[ 5] = fmaf(h, wb.y, accA[ 5]);
            accA[ 6] = fmaf(h, wb.z, accA[ 6]);
            accA[ 7] = fmaf(h, wb.w, accA[ 7]);
            accA[ 8] = fmaf(h, wc.x, accA[ 8]);
            accA[ 9] = fmaf(h, wc.y, accA[ 9]);
            accA[10] = fmaf(h, wc.z, accA[10]);
            accA[11] = fmaf(h, wc.w, accA[11]);
            accA[12] = fmaf(h, wd.x, accA[12]);
            accA[13] = fmaf(h, wd.y, accA[13]);
            accA[14] = fmaf(h, wd.z, accA[14]);
            accA[15] = fmaf(h, wd.w, accA[15]);
        }
        #pragma unroll
        for (int j = 0; j < 16; ++j)
            Hs[lane * 129 + cb + j] = fmaxf(accA[j], 0.0f);   // 2-way free
    }
    __syncthreads();

    // ---------------- Phase B: fc2 ----------------
    float acc[32];
    const int cb2 = w * 32;                       // uniform col base
    #pragma unroll
    for (int j = 0; j < 8; ++j) {
        const float4 b = *(const float4*)(b2 + cb2 + 4 * j);
        acc[4*j+0] = b.x; acc[4*j+1] = b.y; acc[4*j+2] = b.z; acc[4*j+3] = b.w;
    }
    #pragma unroll 2
    for (int k = 0; k < 128; ++k) {
        const float h = Hs[lane * 129 + k];       // 2-way free
        #pragma unroll
        for (int j = 0; j < 8; ++j) {
            const float4 wv = *(const float4*)(W2 + (size_t)k * 256 + cb2 + 4 * j);
            acc[4*j+0] = fmaf(h, wv.x, acc[4*j+0]);
            acc[4*j+1] = fmaf(h, wv.y, acc[4*j+1]);
            acc[4*j+2] = fmaf(h, wv.z, acc[4*j+2]);
            acc[4*j+3] = fmaf(h, wv.w, acc[4*j+3]);
        }
    }
    #pragma unroll
    for (int j = 0; j < 32; ++j) acc[j] = fmaxf(acc[j], 0.0f);

    // ---- epilogue: transpose via Hs, coalesced float4 stores (2 sweeps) ----
    #pragma unroll 1
    for (int s = 0; s < 2; ++s) {
        __syncthreads();                          // Hs free / sweep done
        if ((w >> 2) == s) {                      // waves owning cols [s*128,+128)
            const int cl = cb2 - s * 128;
            #pragma unroll
            for (int j = 0; j < 32; ++j)
                Hs[lane * 129 + cl + j] = acc[j];
        }
        __syncthreads();
        #pragma unroll
        for (int it = 0; it < 4; ++it) {
            const int m = tid + 512 * it;         // float4 idx 0..2047
            const int r = m >> 5, c4 = m & 31;
            float4 o;
            o.x = Hs[r * 129 + c4 * 4 + 0];
            o.y = Hs[r * 129 + c4 * 4 + 1];
            o.z = Hs[r * 129 + c4 * 4 + 2];
            o.w = Hs[r * 129 + c4 * 4 + 3];
            *(float4*)(out + (size_t)(r0b + r) * 256 + s * 128 + c4 * 4) = o;
        }
    }
}

// ---------------------------------------------------------------------------
extern "C" void kernel_launch(void* const* d_in, const int* in_sizes, int n_in,
                              void* d_out, int out_size, void* d_ws, size_t ws_size,
                              hipStream_t stream) {
    const float* points  = (const float*)d_in[0];
    const int*   cluster = (const int*)d_in[1];   // int32 on device (harness)
    const float* W0      = (const float*)d_in[2];
    const float* b0      = (const float*)d_in[3];
    const float* W1      = (const float*)d_in[4];
    const float* b1      = (const float*)d_in[5];
    const float* W2      = (const float*)d_in[6];
    const float* b2      = (const float*)d_in[7];
    float* out = (float*)d_out;

    float* pooled = (float*)d_ws;   // 16 MB

    k_zero<<<(NCLUST * 64 / 4) / 256, 256, 0, stream>>>((float4*)pooled);
    k_fc0_pool<<<N_PTS / 1024, 256, 0, stream>>>(points, cluster, W0, b0, pooled);
    k_mlp<<<NCLUST / 64, 512, 0, stream>>>(pooled, W1, b1, W2, b2, out);
}